// Round 1
// baseline (482.612 us; speedup 1.0000x reference)
//
#include <hip/hip_runtime.h>
#include <math.h>

#define D 1024
#define L 2048
#define B 32

// Kernel 1: u[b][d] = sum_e hidden[b][e] * W[e][d]   (u = hidden @ W, W is [out=e][in=d])
// One block per b; 256 threads, each owns 4 consecutive d via float4.
__global__ void compute_u(const float* __restrict__ hidden,
                          const float* __restrict__ W,
                          float* __restrict__ u) {
    __shared__ float h[D];
    const int b = blockIdx.x;
    const int t = threadIdx.x;  // 0..255
    // stage hidden row (4 KB) into LDS
    ((float4*)h)[t] = ((const float4*)(hidden + (size_t)b * D))[t];
    __syncthreads();
    float4 acc = {0.f, 0.f, 0.f, 0.f};
    const float4* Wrow = (const float4*)W;  // W[e*D + 4t] == Wrow[e*(D/4) + t]
#pragma unroll 4
    for (int e = 0; e < D; ++e) {
        float4 w = Wrow[(size_t)e * (D / 4) + t];
        float hv = h[e];  // LDS broadcast (same addr, all lanes)
        acc.x += hv * w.x;
        acc.y += hv * w.y;
        acc.z += hv * w.z;
        acc.w += hv * w.w;
    }
    ((float4*)(u + (size_t)b * D))[t] = acc;
}

// Kernel 2: scores[b][l] = enc[l,b,:] . u[b,:]
// One 64-lane wave per (l,b) pair. enc[(l*B+b)*D + d] is contiguous in d.
__global__ void compute_scores(const float* __restrict__ enc,
                               const float* __restrict__ u,
                               float* __restrict__ scores) {
    const int wave = threadIdx.x >> 6;  // 0..3
    const int lane = threadIdx.x & 63;
    const int p = blockIdx.x * 4 + wave;  // pair index = l*B + b
    const int b = p & (B - 1);
    const int l = p >> 5;  // p / B
    const float4* e4 = (const float4*)(enc + (size_t)p * D);
    const float4* u4 = (const float4*)(u + (size_t)b * D);
    float acc = 0.f;
#pragma unroll
    for (int i = 0; i < 4; ++i) {  // 4 iters * 64 lanes * 4 floats = 1024
        float4 ev = e4[i * 64 + lane];
        float4 uv = u4[i * 64 + lane];
        acc += ev.x * uv.x + ev.y * uv.y + ev.z * uv.z + ev.w * uv.w;
    }
#pragma unroll
    for (int off = 32; off >= 1; off >>= 1) acc += __shfl_xor(acc, off, 64);
    if (lane == 0) scores[(size_t)b * L + l] = acc;
}

// Kernel 3: out[b,:] = softmax(scores[b,:])  over L=2048. One block per b.
__global__ void softmax_rows(const float* __restrict__ scores,
                             float* __restrict__ out) {
    const int b = blockIdx.x;
    const int t = threadIdx.x;  // 256 threads
    const int lane = t & 63, wv = t >> 6;
    const float* row = scores + (size_t)b * L;
    float v[8];
    float m = -INFINITY;
#pragma unroll
    for (int i = 0; i < 8; ++i) {
        v[i] = row[t + i * 256];
        m = fmaxf(m, v[i]);
    }
#pragma unroll
    for (int off = 32; off >= 1; off >>= 1) m = fmaxf(m, __shfl_xor(m, off, 64));
    __shared__ float redm[4];
    if (lane == 0) redm[wv] = m;
    __syncthreads();
    m = fmaxf(fmaxf(redm[0], redm[1]), fmaxf(redm[2], redm[3]));
    float s = 0.f;
#pragma unroll
    for (int i = 0; i < 8; ++i) {
        v[i] = __expf(v[i] - m);
        s += v[i];
    }
#pragma unroll
    for (int off = 32; off >= 1; off >>= 1) s += __shfl_xor(s, off, 64);
    __shared__ float reds[4];
    if (lane == 0) reds[wv] = s;
    __syncthreads();
    s = reds[0] + reds[1] + reds[2] + reds[3];
    const float inv = 1.f / s;
#pragma unroll
    for (int i = 0; i < 8; ++i) out[(size_t)b * L + t + i * 256] = v[i] * inv;
}

extern "C" void kernel_launch(void* const* d_in, const int* in_sizes, int n_in,
                              void* d_out, int out_size, void* d_ws, size_t ws_size,
                              hipStream_t stream) {
    const float* hidden = (const float*)d_in[0];  // [B, D]
    const float* enc    = (const float*)d_in[1];  // [L, B, D]
    const float* W      = (const float*)d_in[2];  // [D, D]
    // d_in[3] (bias) is provably a no-op under softmax: hidden.b is constant in l.
    float* u      = (float*)d_ws;        // [B, D]  = 128 KB
    float* scores = u + (size_t)B * D;   // [B, L]  = 256 KB
    float* out    = (float*)d_out;       // [B, L]

    compute_u<<<B, 256, 0, stream>>>(hidden, W, u);
    compute_scores<<<(L * B) / 4, 256, 0, stream>>>(enc, u, scores);
    softmax_rows<<<B, 256, 0, stream>>>(scores, out);
}

// Round 2
// 388.272 us; speedup vs baseline: 1.2430x; 1.2430x over previous
//
#include <hip/hip_runtime.h>
#include <math.h>

#define D 1024
#define L 2048
#define B 32

// Kernel 1: u[b][d] += sum_{e in chunk} hidden[b][e] * W[e][d]
// Split the e-reduction 8 ways: grid = 32 b * 8 chunks = 256 blocks (full GPU).
// u must be zeroed before launch (hipMemsetAsync).
__global__ void compute_u_split(const float* __restrict__ hidden,
                                const float* __restrict__ W,
                                float* __restrict__ u) {
    __shared__ float h[128];
    const int b     = blockIdx.x >> 3;   // 0..31
    const int chunk = blockIdx.x & 7;    // 0..7
    const int t = threadIdx.x;           // 0..255, owns columns 4t..4t+3
    if (t < 128) h[t] = hidden[(size_t)b * D + chunk * 128 + t];
    __syncthreads();
    float4 acc = {0.f, 0.f, 0.f, 0.f};
    const float4* Wrow = (const float4*)W;
#pragma unroll 8
    for (int i = 0; i < 128; ++i) {
        const int e = chunk * 128 + i;
        float4 w = Wrow[(size_t)e * (D / 4) + t];
        float hv = h[i];
        acc.x += hv * w.x;
        acc.y += hv * w.y;
        acc.z += hv * w.z;
        acc.w += hv * w.w;
    }
    float* up = u + (size_t)b * D + 4 * t;
    atomicAdd(up + 0, acc.x);
    atomicAdd(up + 1, acc.y);
    atomicAdd(up + 2, acc.z);
    atomicAdd(up + 3, acc.w);
}

// Kernel 2: scores[b][l] = enc[l,b,:] . u[b,:]
// One wave handles 4 consecutive l for ONE b: u row loaded once per wave,
// float4-coalesced enc reads, float4 score store. 4096 blocks * 4 waves.
__global__ void compute_scores(const float* __restrict__ enc,
                               const float* __restrict__ u,
                               float* __restrict__ scores) {
    const int wave = threadIdx.x >> 6;          // 0..3
    const int lane = threadIdx.x & 63;
    const int q = blockIdx.x * 4 + wave;        // wave-task 0..16383
    const int b = q & (B - 1);
    const int lbase = (q >> 5) * 4;             // 0,4,...,2044
    const float4* u4 = (const float4*)(u + (size_t)b * D);
    float4 uv[4];
#pragma unroll
    for (int i = 0; i < 4; ++i) uv[i] = u4[i * 64 + lane];
    float r[4];
#pragma unroll
    for (int j = 0; j < 4; ++j) {
        const float4* e4 = (const float4*)(enc + ((size_t)(lbase + j) * B + b) * D);
        float acc = 0.f;
#pragma unroll
        for (int i = 0; i < 4; ++i) {
            float4 ev = e4[i * 64 + lane];
            acc += ev.x * uv[i].x + ev.y * uv[i].y + ev.z * uv[i].z + ev.w * uv[i].w;
        }
#pragma unroll
        for (int off = 32; off >= 1; off >>= 1) acc += __shfl_xor(acc, off, 64);
        r[j] = acc;
    }
    if (lane == 0) {
        float4 o = {r[0], r[1], r[2], r[3]};
        *(float4*)(scores + (size_t)b * L + lbase) = o;
    }
}

// Kernel 3: out[b,:] = softmax(scores[b,:]) over L=2048. One block per b.
__global__ void softmax_rows(const float* __restrict__ scores,
                             float* __restrict__ out) {
    const int b = blockIdx.x;
    const int t = threadIdx.x;  // 256 threads
    const int lane = t & 63, wv = t >> 6;
    const float* row = scores + (size_t)b * L;
    float v[8];
    float m = -INFINITY;
#pragma unroll
    for (int i = 0; i < 8; ++i) {
        v[i] = row[t + i * 256];
        m = fmaxf(m, v[i]);
    }
#pragma unroll
    for (int off = 32; off >= 1; off >>= 1) m = fmaxf(m, __shfl_xor(m, off, 64));
    __shared__ float redm[4];
    if (lane == 0) redm[wv] = m;
    __syncthreads();
    m = fmaxf(fmaxf(redm[0], redm[1]), fmaxf(redm[2], redm[3]));
    float s = 0.f;
#pragma unroll
    for (int i = 0; i < 8; ++i) {
        v[i] = __expf(v[i] - m);
        s += v[i];
    }
#pragma unroll
    for (int off = 32; off >= 1; off >>= 1) s += __shfl_xor(s, off, 64);
    __shared__ float reds[4];
    if (lane == 0) reds[wv] = s;
    __syncthreads();
    s = reds[0] + reds[1] + reds[2] + reds[3];
    const float inv = 1.f / s;
#pragma unroll
    for (int i = 0; i < 8; ++i) out[(size_t)b * L + t + i * 256] = v[i] * inv;
}

extern "C" void kernel_launch(void* const* d_in, const int* in_sizes, int n_in,
                              void* d_out, int out_size, void* d_ws, size_t ws_size,
                              hipStream_t stream) {
    const float* hidden = (const float*)d_in[0];  // [B, D]
    const float* enc    = (const float*)d_in[1];  // [L, B, D]
    const float* W      = (const float*)d_in[2];  // [D, D]
    // d_in[3] (bias) cancels in the softmax: hidden.b is constant along l.
    float* u      = (float*)d_ws;        // [B, D]  = 128 KB (zeroed below)
    float* scores = u + (size_t)B * D;   // [B, L]  = 256 KB (fully overwritten)
    float* out    = (float*)d_out;       // [B, L]

    hipMemsetAsync(u, 0, (size_t)B * D * sizeof(float), stream);
    compute_u_split<<<B * 8, 256, 0, stream>>>(hidden, W, u);
    compute_scores<<<(L * B) / 16, 256, 0, stream>>>(enc, u, scores);
    softmax_rows<<<B, 256, 0, stream>>>(scores, out);
}

// Round 3
// 369.858 us; speedup vs baseline: 1.3049x; 1.0498x over previous
//
#include <hip/hip_runtime.h>
#include <math.h>

#define D 1024
#define L 2048
#define B 32

typedef float v4f __attribute__((ext_vector_type(4)));

// Kernel 1: u[b][d] += sum_{e in chunk} hidden[b][e] * W[e][d]
// e split 16 ways: grid = 32 b * 16 chunks = 512 blocks (2 blocks/CU, 8 waves/CU).
// u zeroed by hipMemsetAsync before launch.
__global__ void compute_u_split(const float* __restrict__ hidden,
                                const float* __restrict__ W,
                                float* __restrict__ u) {
    __shared__ float h[64];
    const int b     = blockIdx.x >> 4;   // 0..31
    const int chunk = blockIdx.x & 15;   // 0..15, 64 e each
    const int t = threadIdx.x;           // 0..255, owns columns 4t..4t+3
    if (t < 64) h[t] = hidden[(size_t)b * D + chunk * 64 + t];
    __syncthreads();
    float4 acc = {0.f, 0.f, 0.f, 0.f};
    const float4* Wrow = (const float4*)W;
#pragma unroll 8
    for (int i = 0; i < 64; ++i) {
        const int e = chunk * 64 + i;
        float4 w = Wrow[(size_t)e * (D / 4) + t];
        float hv = h[i];
        acc.x += hv * w.x;
        acc.y += hv * w.y;
        acc.z += hv * w.z;
        acc.w += hv * w.w;
    }
    float* up = u + (size_t)b * D + 4 * t;
    atomicAdd(up + 0, acc.x);
    atomicAdd(up + 1, acc.y);
    atomicAdd(up + 2, acc.z);
    atomicAdd(up + 3, acc.w);
}

// Kernel 2: scores[b][l] = enc[l,b,:] . u[b,:]
// One wave handles 8 consecutive l for ONE b. 8192 waves = 2048 blocks.
// enc loads are nontemporal (pure stream, 268 MB > L3).
__global__ void compute_scores(const float* __restrict__ enc,
                               const float* __restrict__ u,
                               float* __restrict__ scores) {
    const int wave = threadIdx.x >> 6;          // 0..3
    const int lane = threadIdx.x & 63;
    const int q = blockIdx.x * 4 + wave;        // 0..8191
    const int b = q & (B - 1);
    const int lbase = (q >> 5) * 8;             // 0,8,...,2040
    const v4f* u4 = (const v4f*)(u + (size_t)b * D);
    v4f uv[4];
#pragma unroll
    for (int i = 0; i < 4; ++i) uv[i] = u4[i * 64 + lane];
    float acc[8];
#pragma unroll
    for (int j = 0; j < 8; ++j) {
        const v4f* e4 = (const v4f*)(enc + ((size_t)(lbase + j) * B + b) * D);
        float a = 0.f;
#pragma unroll
        for (int i = 0; i < 4; ++i) {
            v4f ev = __builtin_nontemporal_load(e4 + i * 64 + lane);
            a += ev.x * uv[i].x + ev.y * uv[i].y + ev.z * uv[i].z + ev.w * uv[i].w;
        }
        acc[j] = a;
    }
#pragma unroll
    for (int j = 0; j < 8; ++j)
#pragma unroll
        for (int off = 32; off >= 1; off >>= 1) acc[j] += __shfl_xor(acc[j], off, 64);
    if (lane == 0) {
        float* sp = scores + (size_t)b * L + lbase;
        float4 o0 = {acc[0], acc[1], acc[2], acc[3]};
        float4 o1 = {acc[4], acc[5], acc[6], acc[7]};
        *(float4*)(sp + 0) = o0;
        *(float4*)(sp + 4) = o1;
    }
}

// Kernel 3: out[b,:] = softmax(scores[b,:]) over L=2048. One block per b, 1024 thr.
__global__ void softmax_rows(const float* __restrict__ scores,
                             float* __restrict__ out) {
    const int b = blockIdx.x;
    const int t = threadIdx.x;           // 0..1023
    const int lane = t & 63, wv = t >> 6;  // 16 waves
    const float* row = scores + (size_t)b * L;
    float v0 = row[t];
    float v1 = row[t + 1024];
    float m = fmaxf(v0, v1);
#pragma unroll
    for (int off = 32; off >= 1; off >>= 1) m = fmaxf(m, __shfl_xor(m, off, 64));
    __shared__ float redm[16];
    __shared__ float reds[16];
    if (lane == 0) redm[wv] = m;
    __syncthreads();
    m = redm[0];
#pragma unroll
    for (int k = 1; k < 16; ++k) m = fmaxf(m, redm[k]);
    v0 = __expf(v0 - m);
    v1 = __expf(v1 - m);
    float s = v0 + v1;
#pragma unroll
    for (int off = 32; off >= 1; off >>= 1) s += __shfl_xor(s, off, 64);
    if (lane == 0) reds[wv] = s;
    __syncthreads();
    s = reds[0];
#pragma unroll
    for (int k = 1; k < 16; ++k) s += reds[k];
    const float inv = 1.f / s;
    out[(size_t)b * L + t] = v0 * inv;
    out[(size_t)b * L + t + 1024] = v1 * inv;
}

extern "C" void kernel_launch(void* const* d_in, const int* in_sizes, int n_in,
                              void* d_out, int out_size, void* d_ws, size_t ws_size,
                              hipStream_t stream) {
    const float* hidden = (const float*)d_in[0];  // [B, D]
    const float* enc    = (const float*)d_in[1];  // [L, B, D]
    const float* W      = (const float*)d_in[2];  // [D, D]
    // d_in[3] (bias) cancels in the softmax: hidden.b is constant along l.
    float* u      = (float*)d_ws;        // [B, D]  = 128 KB (zeroed below)
    float* scores = u + (size_t)B * D;   // [B, L]  = 256 KB (fully overwritten)
    float* out    = (float*)d_out;       // [B, L]

    hipMemsetAsync(u, 0, (size_t)B * D * sizeof(float), stream);
    compute_u_split<<<B * 16, 256, 0, stream>>>(hidden, W, u);
    compute_scores<<<(L * B) / 32, 256, 0, stream>>>(enc, u, scores);
    softmax_rows<<<B, 1024, 0, stream>>>(scores, out);
}